// Round 2
// baseline (644.040 us; speedup 1.0000x reference)
//
#include <hip/hip_runtime.h>

#define DIM 128
#define KK 3
#define NW 384   // KK*DIM
#define NPB 16   // nodes per block in gemm

// ---------- CSR build ----------
__global__ void hist_kernel(const int* __restrict__ eidx, int* __restrict__ deg, int E) {
    int e = blockIdx.x * blockDim.x + threadIdx.x;
    if (e < E) atomicAdd(&deg[eidx[e]], 1);
}

// Exclusive scan of deg[0..n) -> offs, single block of 1024 threads.
__global__ __launch_bounds__(1024) void scan_kernel(const int* __restrict__ deg,
                                                    int* __restrict__ offs, int n) {
    __shared__ int wsum[16];
    int tid = threadIdx.x;
    int chunk = (n + 1023) >> 10;
    int beg = tid * chunk;
    int end = min(beg + chunk, n);
    int s = 0;
    for (int i = beg; i < end; ++i) s += deg[i];
    int lane = tid & 63, wv = tid >> 6;
    int v = s;
    for (int o = 1; o < 64; o <<= 1) {
        int u = __shfl_up(v, o);
        if (lane >= o) v += u;
    }
    if (lane == 63) wsum[wv] = v;
    __syncthreads();
    if (tid == 0) {
        int r = 0;
        for (int i = 0; i < 16; ++i) { int t2 = wsum[i]; wsum[i] = r; r += t2; }
    }
    __syncthreads();
    int off = wsum[wv] + (v - s);  // exclusive prefix at this thread's chunk start
    for (int i = beg; i < end; ++i) { offs[i] = off; off += deg[i]; }
}

// Permute edges into row-grouped records: rec[pos] = {col(bits), t0, t1, t2}
__global__ void fill_kernel(const int* __restrict__ eidx, const float* __restrict__ TT,
                            const int* __restrict__ offs, int* __restrict__ cur,
                            float4* __restrict__ rec, int E) {
    int e = blockIdx.x * blockDim.x + threadIdx.x;
    if (e >= E) return;
    int row = eidx[e];
    int col = eidx[(size_t)E + e];
    int pos = offs[row] + atomicAdd(&cur[row], 1);
    float4 r;
    r.x = __int_as_float(col);
    r.y = TT[e * 3 + 0];
    r.z = TT[e * 3 + 1];
    r.w = TT[e * 3 + 2];
    rec[pos] = r;
}

// ---------- input prep ----------
// weight [i][d][k] -> wt[k*DIM+i][d] (coalesced in d)
__global__ void wt_kernel(const float* __restrict__ w, float* __restrict__ wt) {
    int idx = blockIdx.x * blockDim.x + threadIdx.x;
    if (idx >= DIM * DIM * KK) return;
    int k = idx % KK;
    int d = (idx / KK) % DIM;
    int i = idx / (KK * DIM);
    wt[((size_t)k * DIM + i) * DIM + d] = w[idx];
}

// x f32 -> bf16 (RNE), halves gather traffic
__global__ void xcast_kernel(const float* __restrict__ x, unsigned short* __restrict__ xb, int total) {
    int i = blockIdx.x * blockDim.x + threadIdx.x;
    if (i >= total) return;
    unsigned b = __float_as_uint(x[i]);
    unsigned r = (b + 0x7fffu + ((b >> 16) & 1u)) >> 16;
    xb[i] = (unsigned short)r;
}

// ---------- aggregation core (one wave per row, lane covers d=2*lane, 2*lane+1) ----------
__device__ __forceinline__ void agg_row(const float4* __restrict__ rec,
                                        const int* __restrict__ offs,
                                        const int* __restrict__ deg,
                                        const unsigned* __restrict__ xb2,
                                        int r, int lane,
                                        float& a0l, float& a0h, float& a1l,
                                        float& a1h, float& a2l, float& a2h) {
    a0l = a0h = a1l = a1h = a2l = a2h = 0.f;
    int p = offs[r], pe = p + deg[r];
    for (; p + 2 <= pe; p += 2) {
        float4 rc0 = rec[p], rc1 = rec[p + 1];
        int c0 = __float_as_int(rc0.x), c1 = __float_as_int(rc1.x);
        unsigned u0 = xb2[(size_t)c0 * 64 + lane];
        unsigned u1 = xb2[(size_t)c1 * 64 + lane];
        float x0l = __uint_as_float(u0 << 16), x0h = __uint_as_float(u0 & 0xffff0000u);
        float x1l = __uint_as_float(u1 << 16), x1h = __uint_as_float(u1 & 0xffff0000u);
        a0l = fmaf(rc0.y, x0l, a0l); a0h = fmaf(rc0.y, x0h, a0h);
        a1l = fmaf(rc0.z, x0l, a1l); a1h = fmaf(rc0.z, x0h, a1h);
        a2l = fmaf(rc0.w, x0l, a2l); a2h = fmaf(rc0.w, x0h, a2h);
        a0l = fmaf(rc1.y, x1l, a0l); a0h = fmaf(rc1.y, x1h, a0h);
        a1l = fmaf(rc1.z, x1l, a1l); a1h = fmaf(rc1.z, x1h, a1h);
        a2l = fmaf(rc1.w, x1l, a2l); a2h = fmaf(rc1.w, x1h, a2h);
    }
    if (p < pe) {
        float4 rc0 = rec[p];
        int c0 = __float_as_int(rc0.x);
        unsigned u0 = xb2[(size_t)c0 * 64 + lane];
        float x0l = __uint_as_float(u0 << 16), x0h = __uint_as_float(u0 & 0xffff0000u);
        a0l = fmaf(rc0.y, x0l, a0l); a0h = fmaf(rc0.y, x0h, a0h);
        a1l = fmaf(rc0.z, x0l, a1l); a1h = fmaf(rc0.z, x0h, a1h);
        a2l = fmaf(rc0.w, x0l, a2l); a2h = fmaf(rc0.w, x0h, a2h);
    }
}

// Plan A: z[n][k][d] to global
__global__ __launch_bounds__(256) void agg_kernel(const float4* __restrict__ rec,
        const int* __restrict__ offs, const int* __restrict__ deg,
        const unsigned* __restrict__ xb2, float* __restrict__ z, int n_nodes) {
    int lane = threadIdx.x & 63;
    int wv = threadIdx.x >> 6;
    int r = blockIdx.x * 4 + wv;
    if (r >= n_nodes) return;
    float a0l, a0h, a1l, a1h, a2l, a2h;
    agg_row(rec, offs, deg, xb2, r, lane, a0l, a0h, a1l, a1h, a2l, a2h);
    float2* z2 = (float2*)(z + (size_t)r * NW);
    z2[0 * 64 + lane] = make_float2(a0l, a0h);
    z2[1 * 64 + lane] = make_float2(a1l, a1h);
    z2[2 * 64 + lane] = make_float2(a2l, a2h);
}

// Plan A: out[n][d] = bias[d] + sum_ki z[n][ki] * wt[ki][d]
__global__ __launch_bounds__(128) void gemm_kernel(const float* __restrict__ z,
        const float* __restrict__ wt, const float* __restrict__ bias,
        float* __restrict__ out, int n_nodes) {
    int t = threadIdx.x;
    int n0 = blockIdx.x * NPB;
    const float4* zp[NPB];
#pragma unroll
    for (int j = 0; j < NPB; ++j) {
        int n = n0 + j;
        if (n >= n_nodes) n = 0;
        zp[j] = (const float4*)(z + (size_t)n * NW);
    }
    float acc[NPB];
#pragma unroll
    for (int j = 0; j < NPB; ++j) acc[j] = 0.f;
    for (int kq = 0; kq < NW / 4; ++kq) {
        float w0 = wt[(kq * 4 + 0) * DIM + t];
        float w1 = wt[(kq * 4 + 1) * DIM + t];
        float w2 = wt[(kq * 4 + 2) * DIM + t];
        float w3 = wt[(kq * 4 + 3) * DIM + t];
#pragma unroll
        for (int j = 0; j < NPB; ++j) {
            float4 zv = zp[j][kq];
            acc[j] = fmaf(zv.x, w0, acc[j]);
            acc[j] = fmaf(zv.y, w1, acc[j]);
            acc[j] = fmaf(zv.z, w2, acc[j]);
            acc[j] = fmaf(zv.w, w3, acc[j]);
        }
    }
    float b = bias[t];
#pragma unroll
    for (int j = 0; j < NPB; ++j) {
        int n = n0 + j;
        if (n < n_nodes) out[(size_t)n * DIM + t] = acc[j] + b;
    }
}

// Plan B (small ws): fused agg (LDS z) + gemm, 8 nodes/block, 256 threads
__global__ __launch_bounds__(256) void fused_kernel(const float4* __restrict__ rec,
        const int* __restrict__ offs, const int* __restrict__ deg,
        const unsigned* __restrict__ xb2, const float* __restrict__ wt,
        const float* __restrict__ bias, float* __restrict__ out, int n_nodes) {
    __shared__ float zs[8][NW];
    int lane = threadIdx.x & 63;
    int wv = threadIdx.x >> 6;
    int n0 = blockIdx.x * 8;
#pragma unroll
    for (int pass = 0; pass < 2; ++pass) {
        int j = pass * 4 + wv;
        int r = n0 + j;
        float a0l = 0, a0h = 0, a1l = 0, a1h = 0, a2l = 0, a2h = 0;
        if (r < n_nodes)
            agg_row(rec, offs, deg, xb2, r, lane, a0l, a0h, a1l, a1h, a2l, a2h);
        *(float2*)&zs[j][0 * DIM + 2 * lane] = make_float2(a0l, a0h);
        *(float2*)&zs[j][1 * DIM + 2 * lane] = make_float2(a1l, a1h);
        *(float2*)&zs[j][2 * DIM + 2 * lane] = make_float2(a2l, a2h);
    }
    __syncthreads();
    int t = threadIdx.x & 127;
    int h = threadIdx.x >> 7;  // half covers 4 nodes
    float acc[4] = {0.f, 0.f, 0.f, 0.f};
    for (int kq = 0; kq < NW / 4; ++kq) {
        float w0 = wt[(kq * 4 + 0) * DIM + t];
        float w1 = wt[(kq * 4 + 1) * DIM + t];
        float w2 = wt[(kq * 4 + 2) * DIM + t];
        float w3 = wt[(kq * 4 + 3) * DIM + t];
#pragma unroll
        for (int jj = 0; jj < 4; ++jj) {
            float4 zv = *(const float4*)&zs[h * 4 + jj][kq * 4];
            acc[jj] = fmaf(zv.x, w0, acc[jj]);
            acc[jj] = fmaf(zv.y, w1, acc[jj]);
            acc[jj] = fmaf(zv.z, w2, acc[jj]);
            acc[jj] = fmaf(zv.w, w3, acc[jj]);
        }
    }
    float b = bias[t];
#pragma unroll
    for (int jj = 0; jj < 4; ++jj) {
        int n = n0 + h * 4 + jj;
        if (n < n_nodes) out[(size_t)n * DIM + t] = acc[jj] + b;
    }
}

extern "C" void kernel_launch(void* const* d_in, const int* in_sizes, int n_in,
                              void* d_out, int out_size, void* d_ws, size_t ws_size,
                              hipStream_t stream) {
    const float* x    = (const float*)d_in[0];
    const float* TT   = (const float*)d_in[1];
    const float* w    = (const float*)d_in[2];
    const float* bias = (const float*)d_in[3];
    const int*   eidx = (const int*)d_in[4];
    float* out = (float*)d_out;

    int n_nodes = in_sizes[0] / DIM;   // 50000
    int E       = in_sizes[1] / KK;    // 800000

    char* ws = (char*)d_ws;
    size_t o = 0;
    auto take = [&](size_t b) { void* p = ws + o; o += (b + 255) & ~(size_t)255; return p; };
    float4*   rec  = (float4*)take((size_t)E * 16);
    int*      deg  = (int*)take((size_t)n_nodes * 4);
    int*      cur  = (int*)take((size_t)n_nodes * 4);
    int*      offs = (int*)take((size_t)n_nodes * 4);
    float*    wt   = (float*)take((size_t)KK * DIM * DIM * 4);
    unsigned* xb2  = (unsigned*)take((size_t)n_nodes * DIM * 2);
    float*    z    = (float*)(ws + o);
    bool planA = (o + (size_t)n_nodes * NW * 4) <= ws_size;

    hipMemsetAsync(deg, 0, (size_t)n_nodes * 4, stream);
    hipMemsetAsync(cur, 0, (size_t)n_nodes * 4, stream);

    int eblk = (E + 255) / 256;
    hist_kernel<<<eblk, 256, 0, stream>>>(eidx, deg, E);
    scan_kernel<<<1, 1024, 0, stream>>>(deg, offs, n_nodes);
    fill_kernel<<<eblk, 256, 0, stream>>>(eidx, TT, offs, cur, rec, E);
    wt_kernel<<<(DIM * DIM * KK + 255) / 256, 256, 0, stream>>>(w, wt);
    xcast_kernel<<<(n_nodes * DIM + 255) / 256, 256, 0, stream>>>(x, (unsigned short*)xb2, n_nodes * DIM);

    if (planA) {
        agg_kernel<<<(n_nodes + 3) / 4, 256, 0, stream>>>(rec, offs, deg, xb2, z, n_nodes);
        gemm_kernel<<<(n_nodes + NPB - 1) / NPB, 128, 0, stream>>>(z, wt, bias, out, n_nodes);
    } else {
        fused_kernel<<<(n_nodes + 7) / 8, 256, 0, stream>>>(rec, offs, deg, xb2, wt, bias, out, n_nodes);
    }
}

// Round 3
// 333.826 us; speedup vs baseline: 1.9293x; 1.9293x over previous
//
#include <hip/hip_runtime.h>

#define DIM 128
#define KK 3
#define NW 384      // KK*DIM
#define RPB 16      // rows per fused block

// ---------------- CSR build ----------------
__global__ void hist_kernel(const int* __restrict__ eidx, int* __restrict__ deg, int E) {
    int e = blockIdx.x * blockDim.x + threadIdx.x;
    if (e < E) atomicAdd(&deg[eidx[e]], 1);
}

// scan1: per-256-block partial sums of deg
__global__ __launch_bounds__(256) void scan1_kernel(const int* __restrict__ deg,
                                                    int* __restrict__ bsum, int n) {
    int i = blockIdx.x * 256 + threadIdx.x;
    int v = (i < n) ? deg[i] : 0;
    for (int o = 32; o; o >>= 1) v += __shfl_down(v, o);
    __shared__ int ws_[4];
    int lane = threadIdx.x & 63, wv = threadIdx.x >> 6;
    if (lane == 0) ws_[wv] = v;
    __syncthreads();
    if (threadIdx.x == 0) bsum[blockIdx.x] = ws_[0] + ws_[1] + ws_[2] + ws_[3];
}

// scan2: exclusive scan of bsum[nb] in-place (nb <= 256), one block
__global__ __launch_bounds__(256) void scan2_kernel(int* __restrict__ bsum, int nb) {
    int t = threadIdx.x;
    int v = (t < nb) ? bsum[t] : 0;
    int lane = t & 63, wv = t >> 6;
    int inc = v;
    for (int o = 1; o < 64; o <<= 1) { int u = __shfl_up(inc, o); if (lane >= o) inc += u; }
    __shared__ int wsum[4];
    if (lane == 63) wsum[wv] = inc;
    __syncthreads();
    if (t == 0) { int r = 0; for (int i = 0; i < 4; ++i) { int x = wsum[i]; wsum[i] = r; r += x; } }
    __syncthreads();
    if (t < nb) bsum[t] = wsum[wv] + inc - v;
}

// scan3: offs[i] = bsum[blk] + intra-block exclusive; also cur[i]=offs[i], offs[n]=total
__global__ __launch_bounds__(256) void scan3_kernel(const int* __restrict__ deg,
        const int* __restrict__ bsum, int* __restrict__ offs, int* __restrict__ cur, int n) {
    int t = threadIdx.x;
    int i = blockIdx.x * 256 + t;
    int v = (i < n) ? deg[i] : 0;
    int lane = t & 63, wv = t >> 6;
    int inc = v;
    for (int o = 1; o < 64; o <<= 1) { int u = __shfl_up(inc, o); if (lane >= o) inc += u; }
    __shared__ int wsum[4];
    if (lane == 63) wsum[wv] = inc;
    __syncthreads();
    if (t == 0) { int r = 0; for (int j = 0; j < 4; ++j) { int x = wsum[j]; wsum[j] = r; r += x; } }
    __syncthreads();
    int exc = bsum[blockIdx.x] + wsum[wv] + inc - v;
    if (i < n) {
        offs[i] = exc;
        cur[i] = exc;
        if (i == n - 1) offs[n] = exc + v;
    }
}

// fill: rec[pos] = {col_bits, t0, t1, t2} grouped by row
__global__ void fill_kernel(const int* __restrict__ eidx, const float* __restrict__ TT,
                            int* __restrict__ cur, float4* __restrict__ rec, int E) {
    int e = blockIdx.x * blockDim.x + threadIdx.x;
    if (e >= E) return;
    int row = eidx[e];
    int col = eidx[(size_t)E + e];
    int pos = atomicAdd(&cur[row], 1);
    float4 r;
    r.x = __int_as_float(col);
    r.y = TT[e * 3 + 0];
    r.z = TT[e * 3 + 1];
    r.w = TT[e * 3 + 2];
    rec[pos] = r;
}

// ---------------- input prep ----------------
// weight [i][DIM d][K k] -> wtq[kq][d][c] where ki=kq*4+c (ki = k*DIM+i flattened as in zs)
__global__ void wtq_kernel(const float* __restrict__ w, float* __restrict__ wtq) {
    int idx = blockIdx.x * blockDim.x + threadIdx.x;
    if (idx >= (NW / 4) * DIM * 4) return;
    int c  = idx & 3;
    int d  = (idx >> 2) & (DIM - 1);
    int kq = idx >> 9;
    int ki = kq * 4 + c;          // ki = k*DIM + i
    int k  = ki >> 7;             // which of the 3 kernels
    int i  = ki & (DIM - 1);      // input feature
    wtq[idx] = w[((size_t)i * DIM + d) * KK + k];
}

// x f32 -> bf16 (RNE)
__global__ void xcast_kernel(const float* __restrict__ x, unsigned short* __restrict__ xb, int total) {
    int i = blockIdx.x * blockDim.x + threadIdx.x;
    if (i >= total) return;
    unsigned b = __float_as_uint(x[i]);
    xb[i] = (unsigned short)((b + 0x7fffu + ((b >> 16) & 1u)) >> 16);
}

// ---------------- fused aggregate (LDS z) + gemm ----------------
__global__ __launch_bounds__(256) void fused_kernel(const float4* __restrict__ rec,
        const int* __restrict__ offs, const unsigned* __restrict__ xb2,
        const float* __restrict__ wtq, const float* __restrict__ bias,
        float* __restrict__ out, int n) {
    __shared__ float zs[RPB][NW];
    int lane = threadIdx.x & 63, wv = threadIdx.x >> 6;
    int n0 = blockIdx.x * RPB;

#pragma unroll
    for (int pass = 0; pass < RPB / 4; ++pass) {
        int j = pass * 4 + wv;
        int r = n0 + j;
        float a0l = 0, a0h = 0, a1l = 0, a1h = 0, a2l = 0, a2h = 0;
        if (r < n) {
            int p = offs[r], pe = offs[r + 1];
            for (; p + 4 <= pe; p += 4) {
                float4 r0 = rec[p], r1 = rec[p + 1], r2 = rec[p + 2], r3 = rec[p + 3];
                unsigned u0 = xb2[(size_t)__float_as_int(r0.x) * 64 + lane];
                unsigned u1 = xb2[(size_t)__float_as_int(r1.x) * 64 + lane];
                unsigned u2 = xb2[(size_t)__float_as_int(r2.x) * 64 + lane];
                unsigned u3 = xb2[(size_t)__float_as_int(r3.x) * 64 + lane];
                float xl, xh;
                xl = __uint_as_float(u0 << 16); xh = __uint_as_float(u0 & 0xffff0000u);
                a0l = fmaf(r0.y, xl, a0l); a0h = fmaf(r0.y, xh, a0h);
                a1l = fmaf(r0.z, xl, a1l); a1h = fmaf(r0.z, xh, a1h);
                a2l = fmaf(r0.w, xl, a2l); a2h = fmaf(r0.w, xh, a2h);
                xl = __uint_as_float(u1 << 16); xh = __uint_as_float(u1 & 0xffff0000u);
                a0l = fmaf(r1.y, xl, a0l); a0h = fmaf(r1.y, xh, a0h);
                a1l = fmaf(r1.z, xl, a1l); a1h = fmaf(r1.z, xh, a1h);
                a2l = fmaf(r1.w, xl, a2l); a2h = fmaf(r1.w, xh, a2h);
                xl = __uint_as_float(u2 << 16); xh = __uint_as_float(u2 & 0xffff0000u);
                a0l = fmaf(r2.y, xl, a0l); a0h = fmaf(r2.y, xh, a0h);
                a1l = fmaf(r2.z, xl, a1l); a1h = fmaf(r2.z, xh, a1h);
                a2l = fmaf(r2.w, xl, a2l); a2h = fmaf(r2.w, xh, a2h);
                xl = __uint_as_float(u3 << 16); xh = __uint_as_float(u3 & 0xffff0000u);
                a0l = fmaf(r3.y, xl, a0l); a0h = fmaf(r3.y, xh, a0h);
                a1l = fmaf(r3.z, xl, a1l); a1h = fmaf(r3.z, xh, a1h);
                a2l = fmaf(r3.w, xl, a2l); a2h = fmaf(r3.w, xh, a2h);
            }
            for (; p < pe; ++p) {
                float4 r0 = rec[p];
                unsigned u0 = xb2[(size_t)__float_as_int(r0.x) * 64 + lane];
                float xl = __uint_as_float(u0 << 16), xh = __uint_as_float(u0 & 0xffff0000u);
                a0l = fmaf(r0.y, xl, a0l); a0h = fmaf(r0.y, xh, a0h);
                a1l = fmaf(r0.z, xl, a1l); a1h = fmaf(r0.z, xh, a1h);
                a2l = fmaf(r0.w, xl, a2l); a2h = fmaf(r0.w, xh, a2h);
            }
        }
        *(float2*)&zs[j][0 * DIM + 2 * lane] = make_float2(a0l, a0h);
        *(float2*)&zs[j][1 * DIM + 2 * lane] = make_float2(a1l, a1h);
        *(float2*)&zs[j][2 * DIM + 2 * lane] = make_float2(a2l, a2h);
    }
    __syncthreads();

    // gemm phase: out[n0+h*8+jj][t] = bias[t] + sum_ki zs[h*8+jj][ki]*W[ki][t]
    int t = threadIdx.x & 127;
    int h = threadIdx.x >> 7;
    float acc[8] = {0, 0, 0, 0, 0, 0, 0, 0};
    const float4* wq = (const float4*)wtq;
    for (int kq = 0; kq < NW / 4; ++kq) {
        float4 wvq = wq[kq * DIM + t];
#pragma unroll
        for (int jj = 0; jj < 8; ++jj) {
            float4 zv = *(const float4*)&zs[h * 8 + jj][kq * 4];
            acc[jj] = fmaf(zv.x, wvq.x, acc[jj]);
            acc[jj] = fmaf(zv.y, wvq.y, acc[jj]);
            acc[jj] = fmaf(zv.z, wvq.z, acc[jj]);
            acc[jj] = fmaf(zv.w, wvq.w, acc[jj]);
        }
    }
    float b = bias[t];
#pragma unroll
    for (int jj = 0; jj < 8; ++jj) {
        int nn = n0 + h * 8 + jj;
        if (nn < n) out[(size_t)nn * DIM + t] = acc[jj] + b;
    }
}

extern "C" void kernel_launch(void* const* d_in, const int* in_sizes, int n_in,
                              void* d_out, int out_size, void* d_ws, size_t ws_size,
                              hipStream_t stream) {
    const float* x    = (const float*)d_in[0];
    const float* TT   = (const float*)d_in[1];
    const float* w    = (const float*)d_in[2];
    const float* bias = (const float*)d_in[3];
    const int*   eidx = (const int*)d_in[4];
    float* out = (float*)d_out;

    int n = in_sizes[0] / DIM;   // 50000
    int E = in_sizes[1] / KK;    // 800000

    char* ws = (char*)d_ws;
    size_t o = 0;
    auto take = [&](size_t b) { void* p = ws + o; o += (b + 255) & ~(size_t)255; return p; };
    float4*   rec  = (float4*)take((size_t)E * 16);
    int*      deg  = (int*)take((size_t)n * 4);
    int*      offs = (int*)take((size_t)(n + 1) * 4);
    int*      cur  = (int*)take((size_t)n * 4);
    int*      bsum = (int*)take(256 * 4);
    float*    wtq  = (float*)take((size_t)NW * DIM * 4);
    unsigned* xb2  = (unsigned*)take((size_t)n * DIM * 2);
    (void)ws_size;

    hipMemsetAsync(deg, 0, (size_t)n * 4, stream);

    int nb = (n + 255) / 256;          // 196
    int eblk = (E + 255) / 256;
    hist_kernel<<<eblk, 256, 0, stream>>>(eidx, deg, E);
    scan1_kernel<<<nb, 256, 0, stream>>>(deg, bsum, n);
    scan2_kernel<<<1, 256, 0, stream>>>(bsum, nb);
    scan3_kernel<<<nb, 256, 0, stream>>>(deg, bsum, offs, cur, n);
    fill_kernel<<<eblk, 256, 0, stream>>>(eidx, TT, cur, rec, E);
    wtq_kernel<<<(NW * DIM + 255) / 256, 256, 0, stream>>>(w, wtq);
    xcast_kernel<<<(n * DIM + 255) / 256, 256, 0, stream>>>(x, (unsigned short*)xb2, n * DIM);

    fused_kernel<<<(n + RPB - 1) / RPB, 256, 0, stream>>>(rec, offs, xb2, wtq, bias, out, n);
}

// Round 4
// 235.619 us; speedup vs baseline: 2.7334x; 1.4168x over previous
//
#include <hip/hip_runtime.h>
#include <hip/hip_fp16.h>

#define DIM 128
#define KK 3
#define NW 384      // KK*DIM
#define RPB 16      // rows per fused block (one MFMA M-tile)
#define ZPAD 392    // 384 + 8 pad shorts -> bank-spread ds_read_b128

typedef __attribute__((ext_vector_type(4))) float f32x4;
typedef __attribute__((ext_vector_type(8))) short bf16x8;

__device__ __forceinline__ unsigned pkbf(float lo, float hi) {
    unsigned a = __float_as_uint(lo), b = __float_as_uint(hi);
    a = (a + 0x7fffu + ((a >> 16) & 1u)) >> 16;
    b = (b + 0x7fffu + ((b >> 16) & 1u)) & 0xffff0000u;
    return (a & 0xffffu) | b;
}

// ---------- prep: xcast (f32->bf16x2) + deg zero + W bf16 B-fragments ----------
// wbf fragment order: [(kt*8+nt)*64+lane] = 8 bf16 of B[k=kt*32+quad*8+j][n=nt*16+(lane&15)]
__global__ __launch_bounds__(256) void prep_kernel(
        const float* __restrict__ x, const float* __restrict__ w,
        uint2* __restrict__ xb2q, int4* __restrict__ deg4, bf16x8* __restrict__ wbf,
        int xq_total, int dq_total, int xblk, int dblk) {
    int b = blockIdx.x;
    if (b < xblk) {
        int i = b * 256 + threadIdx.x;
        if (i < xq_total) {
            float4 v = ((const float4*)x)[i];
            xb2q[i] = make_uint2(pkbf(v.x, v.y), pkbf(v.z, v.w));
        }
    } else if (b < xblk + dblk) {
        int i = (b - xblk) * 256 + threadIdx.x;
        if (i < dq_total) deg4[i] = make_int4(0, 0, 0, 0);
    } else {
        int t = (b - xblk - dblk) * 256 + threadIdx.x;
        if (t < 12 * 8 * 64) {
            int lane = t & 63;
            int quad = lane >> 4;
            int nn = ((t >> 6) & 7) * 16 + (lane & 15);
            int kbase = (t >> 9) * 32 + quad * 8;
            short vals[8];
#pragma unroll
            for (int j = 0; j < 8; ++j) {
                int k = kbase + j;
                int k3 = k >> 7, i2 = k & (DIM - 1);
                unsigned bv = __float_as_uint(w[((size_t)i2 * DIM + nn) * KK + k3]);
                vals[j] = (short)((bv + 0x7fffu + ((bv >> 16) & 1u)) >> 16);
            }
            wbf[t] = *(const bf16x8*)vals;
        }
    }
}

// ---------- CSR build ----------
__global__ void hist_kernel(const int* __restrict__ eidx, int* __restrict__ deg, int E) {
    int e = blockIdx.x * blockDim.x + threadIdx.x;
    if (e < E) atomicAdd(&deg[eidx[e]], 1);
}

__global__ __launch_bounds__(256) void scan1_kernel(const int* __restrict__ deg,
                                                    int* __restrict__ bsum, int n) {
    int i = blockIdx.x * 256 + threadIdx.x;
    int v = (i < n) ? deg[i] : 0;
    for (int o = 32; o; o >>= 1) v += __shfl_down(v, o);
    __shared__ int ws_[4];
    int lane = threadIdx.x & 63, wv = threadIdx.x >> 6;
    if (lane == 0) ws_[wv] = v;
    __syncthreads();
    if (threadIdx.x == 0) bsum[blockIdx.x] = ws_[0] + ws_[1] + ws_[2] + ws_[3];
}

__global__ __launch_bounds__(256) void scan2_kernel(int* __restrict__ bsum, int nb) {
    int t = threadIdx.x;
    int v = (t < nb) ? bsum[t] : 0;
    int lane = t & 63, wv = t >> 6;
    int inc = v;
    for (int o = 1; o < 64; o <<= 1) { int u = __shfl_up(inc, o); if (lane >= o) inc += u; }
    __shared__ int wsum[4];
    if (lane == 63) wsum[wv] = inc;
    __syncthreads();
    if (t == 0) { int r = 0; for (int i = 0; i < 4; ++i) { int xx = wsum[i]; wsum[i] = r; r += xx; } }
    __syncthreads();
    if (t < nb) bsum[t] = wsum[wv] + inc - v;
}

__global__ __launch_bounds__(256) void scan3_kernel(const int* __restrict__ deg,
        const int* __restrict__ bsum, int* __restrict__ offs, int* __restrict__ cur, int n) {
    int t = threadIdx.x;
    int i = blockIdx.x * 256 + t;
    int v = (i < n) ? deg[i] : 0;
    int lane = t & 63, wv = t >> 6;
    int inc = v;
    for (int o = 1; o < 64; o <<= 1) { int u = __shfl_up(inc, o); if (lane >= o) inc += u; }
    __shared__ int wsum[4];
    if (lane == 63) wsum[wv] = inc;
    __syncthreads();
    if (t == 0) { int r = 0; for (int j = 0; j < 4; ++j) { int xx = wsum[j]; wsum[j] = r; r += xx; } }
    __syncthreads();
    int exc = bsum[blockIdx.x] + wsum[wv] + inc - v;
    if (i < n) {
        offs[i] = exc;
        cur[i] = exc;
        if (i == n - 1) offs[n] = exc + v;
    }
}

// rec[pos] = {col | t0h<<16, t1h | t2h<<16}  (col < 65536 -- N=50000)
__global__ void fill_kernel(const int* __restrict__ eidx, const float* __restrict__ TT,
                            int* __restrict__ cur, uint2* __restrict__ rec, int E) {
    int e = blockIdx.x * blockDim.x + threadIdx.x;
    if (e >= E) return;
    int row = eidx[e];
    unsigned col = (unsigned)eidx[(size_t)E + e];
    unsigned h0 = __half_as_ushort(__float2half_rn(TT[e * 3 + 0]));
    unsigned h1 = __half_as_ushort(__float2half_rn(TT[e * 3 + 1]));
    unsigned h2 = __half_as_ushort(__float2half_rn(TT[e * 3 + 2]));
    int pos = atomicAdd(&cur[row], 1);
    rec[pos] = make_uint2(col | (h0 << 16), h1 | (h2 << 16));
}

// ---------- fused: CSR aggregate into LDS z (bf16) + MFMA gemm ----------
__device__ __forceinline__ void edge_fma(uint2 rc, const unsigned* __restrict__ xb2, int lane,
        float& a0l, float& a0h, float& a1l, float& a1h, float& a2l, float& a2h) {
    int c = rc.x & 0xffffu;
    float t0 = __half2float(__ushort_as_half((unsigned short)(rc.x >> 16)));
    float t1 = __half2float(__ushort_as_half((unsigned short)(rc.y & 0xffffu)));
    float t2 = __half2float(__ushort_as_half((unsigned short)(rc.y >> 16)));
    unsigned u = xb2[(size_t)c * 64 + lane];
    float xl = __uint_as_float(u << 16), xh = __uint_as_float(u & 0xffff0000u);
    a0l = fmaf(t0, xl, a0l); a0h = fmaf(t0, xh, a0h);
    a1l = fmaf(t1, xl, a1l); a1h = fmaf(t1, xh, a1h);
    a2l = fmaf(t2, xl, a2l); a2h = fmaf(t2, xh, a2h);
}

__global__ __launch_bounds__(256) void fused_kernel(const uint2* __restrict__ rec,
        const int* __restrict__ offs, const unsigned* __restrict__ xb2,
        const bf16x8* __restrict__ wbf, const float* __restrict__ bias,
        float* __restrict__ out, int n) {
    __shared__ short zs16[RPB][ZPAD];
    int lane = threadIdx.x & 63, wv = threadIdx.x >> 6;
    int n0 = blockIdx.x * RPB;

#pragma unroll
    for (int pass = 0; pass < RPB / 4; ++pass) {
        int j = pass * 4 + wv;
        int r = n0 + j;
        float a0l = 0, a0h = 0, a1l = 0, a1h = 0, a2l = 0, a2h = 0;
        if (r < n) {
            int p = offs[r], pe = offs[r + 1];
            for (; p + 4 <= pe; p += 4) {
                uint2 r0 = rec[p], r1 = rec[p + 1], r2 = rec[p + 2], r3 = rec[p + 3];
                edge_fma(r0, xb2, lane, a0l, a0h, a1l, a1h, a2l, a2h);
                edge_fma(r1, xb2, lane, a0l, a0h, a1l, a1h, a2l, a2h);
                edge_fma(r2, xb2, lane, a0l, a0h, a1l, a1h, a2l, a2h);
                edge_fma(r3, xb2, lane, a0l, a0h, a1l, a1h, a2l, a2h);
            }
            for (; p < pe; ++p)
                edge_fma(rec[p], xb2, lane, a0l, a0h, a1l, a1h, a2l, a2h);
        }
        *(unsigned*)&zs16[j][0 * DIM + 2 * lane] = pkbf(a0l, a0h);
        *(unsigned*)&zs16[j][1 * DIM + 2 * lane] = pkbf(a1l, a1h);
        *(unsigned*)&zs16[j][2 * DIM + 2 * lane] = pkbf(a2l, a2h);
    }
    __syncthreads();

    // MFMA: M=16 rows (this block), N=128 (8 tiles, 2 per wave), K=384 (12 steps)
    int quad = lane >> 4, m = lane & 15;
    int nt0 = wv * 2, nt1 = wv * 2 + 1;
    f32x4 acc0 = {0.f, 0.f, 0.f, 0.f}, acc1 = {0.f, 0.f, 0.f, 0.f};
#pragma unroll
    for (int kt = 0; kt < 12; ++kt) {
        bf16x8 a  = *(const bf16x8*)&zs16[m][kt * 32 + quad * 8];
        bf16x8 b0 = wbf[(kt * 8 + nt0) * 64 + lane];
        bf16x8 b1 = wbf[(kt * 8 + nt1) * 64 + lane];
        acc0 = __builtin_amdgcn_mfma_f32_16x16x32_bf16(a, b0, acc0, 0, 0, 0);
        acc1 = __builtin_amdgcn_mfma_f32_16x16x32_bf16(a, b1, acc1, 0, 0, 0);
    }
    // C/D layout: col(n)=lane&15, row(m)=quad*4+reg  [m89-verified]
    float bi0 = bias[nt0 * 16 + m], bi1 = bias[nt1 * 16 + m];
#pragma unroll
    for (int rr = 0; rr < 4; ++rr) {
        int node = n0 + quad * 4 + rr;
        if (node < n) {
            out[(size_t)node * DIM + nt0 * 16 + m] = acc0[rr] + bi0;
            out[(size_t)node * DIM + nt1 * 16 + m] = acc1[rr] + bi1;
        }
    }
}

extern "C" void kernel_launch(void* const* d_in, const int* in_sizes, int n_in,
                              void* d_out, int out_size, void* d_ws, size_t ws_size,
                              hipStream_t stream) {
    const float* x    = (const float*)d_in[0];
    const float* TT   = (const float*)d_in[1];
    const float* w    = (const float*)d_in[2];
    const float* bias = (const float*)d_in[3];
    const int*   eidx = (const int*)d_in[4];
    float* out = (float*)d_out;

    int n = in_sizes[0] / DIM;   // 50000 (< 65536: col packed in 16 bits)
    int E = in_sizes[1] / KK;    // 800000

    char* ws = (char*)d_ws;
    size_t o = 0;
    auto take = [&](size_t b) { void* p = ws + o; o += (b + 255) & ~(size_t)255; return p; };
    uint2*    rec  = (uint2*)take((size_t)E * 8);
    int*      deg  = (int*)take((size_t)n * 4);
    int*      offs = (int*)take((size_t)(n + 1) * 4);
    int*      cur  = (int*)take((size_t)n * 4);
    int*      bsum = (int*)take(256 * 4);
    bf16x8*   wbf  = (bf16x8*)take((size_t)12 * 8 * 64 * 16);
    unsigned* xb2  = (unsigned*)take((size_t)n * DIM * 2);
    (void)ws_size;

    int xq = n * DIM / 4, dq = n / 4;
    int xblk = (xq + 255) / 256, dblk = (dq + 255) / 256, wblk = 24;
    prep_kernel<<<xblk + dblk + wblk, 256, 0, stream>>>(
        x, w, (uint2*)xb2, (int4*)deg, wbf, xq, dq, xblk, dblk);

    int nb = (n + 255) / 256;          // 196
    int eblk = (E + 255) / 256;
    hist_kernel<<<eblk, 256, 0, stream>>>(eidx, deg, E);
    scan1_kernel<<<nb, 256, 0, stream>>>(deg, bsum, n);
    scan2_kernel<<<1, 256, 0, stream>>>(bsum, nb);
    scan3_kernel<<<nb, 256, 0, stream>>>(deg, bsum, offs, cur, n);
    fill_kernel<<<eblk, 256, 0, stream>>>(eidx, TT, cur, rec, E);

    fused_kernel<<<(n + RPB - 1) / RPB, 256, 0, stream>>>(rec, offs, xb2, wbf, bias, out, n);
}

// Round 5
// 221.387 us; speedup vs baseline: 2.9091x; 1.0643x over previous
//
#include <hip/hip_runtime.h>
#include <hip/hip_fp16.h>

#define DIM 128
#define KK 3
#define RPB 16      // rows per fused block (one MFMA M-tile)
#define ZPAD 392    // 384 + 8 pad shorts
#define NSH 8       // shards = XCD count

typedef __attribute__((ext_vector_type(4))) float f32x4;
typedef __attribute__((ext_vector_type(8))) short bf16x8;

__device__ __forceinline__ unsigned pkbf(float lo, float hi) {
    unsigned a = __float_as_uint(lo), b = __float_as_uint(hi);
    a = (a + 0x7fffu + ((a >> 16) & 1u)) >> 16;
    b = (b + 0x7fffu + ((b >> 16) & 1u)) & 0xffff0000u;
    return (a & 0xffffu) | b;
}

// exclusive scan of v over a 256-thread block
__device__ __forceinline__ int block_excl_scan(int v, int t) {
    int lane = t & 63, wv = t >> 6;
    int inc = v;
    for (int o = 1; o < 64; o <<= 1) { int u = __shfl_up(inc, o); if (lane >= o) inc += u; }
    __shared__ int wsum[4];
    if (lane == 63) wsum[wv] = inc;
    __syncthreads();
    if (t == 0) { int r = 0; for (int i = 0; i < 4; ++i) { int x = wsum[i]; wsum[i] = r; r += x; } }
    __syncthreads();
    return wsum[wv] + inc - v;
}

// ---------- K1: xcast + W B-fragments + sharded histogram ----------
// wbf fragment order: [(kt*8+nt)*64+lane] = 8 bf16 of B[k=kt*32+quad*8+j][n=nt*16+(lane&15)]
__global__ __launch_bounds__(256) void k1_kernel(
        const float* __restrict__ x, const float* __restrict__ w,
        const int* __restrict__ eidx, uint2* __restrict__ xb2q,
        bf16x8* __restrict__ wbf, int* __restrict__ hist8,
        int xq_total, int xblk, int E, int n) {
    int b = blockIdx.x;
    if (b < xblk) {
        int i = b * 256 + threadIdx.x;
        if (i < xq_total) {
            float4 v = ((const float4*)x)[i];
            xb2q[i] = make_uint2(pkbf(v.x, v.y), pkbf(v.z, v.w));
        }
    } else if (b < xblk + 24) {
        int t = (b - xblk) * 256 + threadIdx.x;
        if (t < 12 * 8 * 64) {
            int lane = t & 63;
            int quad = lane >> 4;
            int nn = ((t >> 6) & 7) * 16 + (lane & 15);
            int kbase = (t >> 9) * 32 + quad * 8;
            short vals[8];
#pragma unroll
            for (int j = 0; j < 8; ++j) {
                int k = kbase + j;
                int k3 = k >> 7, i2 = k & (DIM - 1);
                unsigned bv = __float_as_uint(w[((size_t)i2 * DIM + nn) * KK + k3]);
                vals[j] = (short)((bv + 0x7fffu + ((bv >> 16) & 1u)) >> 16);
            }
            wbf[t] = *(const bf16x8*)vals;
        }
    } else {
        int br = b - xblk - 24;              // hist block index == e>>8
        int e = br * 256 + threadIdx.x;
        if (e < E) {
            int row = eidx[e];
            int s = br & (NSH - 1);          // must match fill's blockIdx&7
            atomicAdd(&hist8[(size_t)s * n + row], 1);
        }
    }
}

// ---------- K2: partial sums (A: hist8[m8], B: deg from 8 strided hist8 planes) ----------
__global__ __launch_bounds__(256) void scan1_kernel(const int* __restrict__ hist8,
        int* __restrict__ bsumA, int* __restrict__ deg, int* __restrict__ bsumB,
        int m8, int n, int blkA) {
    int b = blockIdx.x, t = threadIdx.x;
    int v = 0;
    if (b < blkA) {
        int i = b * 256 + t;
        if (i < m8) v = hist8[i];
    } else {
        int r = (b - blkA) * 256 + t;
        if (r < n) {
            int d = 0;
#pragma unroll
            for (int s = 0; s < NSH; ++s) d += hist8[(size_t)s * n + r];
            deg[r] = d;
            v = d;
        }
    }
    for (int o = 32; o; o >>= 1) v += __shfl_down(v, o);
    __shared__ int ws_[4];
    if ((t & 63) == 0) ws_[t >> 6] = v;
    __syncthreads();
    if (t == 0) {
        int s_ = ws_[0] + ws_[1] + ws_[2] + ws_[3];
        if (b < blkA) bsumA[b] = s_; else bsumB[b - blkA] = s_;
    }
}

// ---------- K3: exclusive scan of bsumA (block 0) and bsumB (block 1), chunked ----------
__global__ __launch_bounds__(256) void scan2_kernel(int* __restrict__ bsumA, int nA,
                                                    int* __restrict__ bsumB, int nB) {
    int* arr = blockIdx.x ? bsumB : bsumA;
    int nn = blockIdx.x ? nB : nA;
    int t = threadIdx.x;
    int chunk = (nn + 255) >> 8;
    int beg = t * chunk, end = min(beg + chunk, nn);
    int s = 0;
    for (int i = beg; i < end; ++i) s += arr[i];
    int run = block_excl_scan(s, t);
    for (int i = beg; i < end; ++i) { int v = arr[i]; arr[i] = run; run += v; }
}

// ---------- K4: offs8/cur8 (A-range) and offs (B-range) ----------
__global__ __launch_bounds__(256) void scan3_kernel(const int* __restrict__ hist8,
        const int* __restrict__ bsumA, const int* __restrict__ deg,
        const int* __restrict__ bsumB, int* __restrict__ offs8, int* __restrict__ cur8,
        int* __restrict__ offs, int m8, int n, int blkA) {
    int b = blockIdx.x, t = threadIdx.x;
    if (b < blkA) {
        int i = b * 256 + t;
        int v = (i < m8) ? hist8[i] : 0;
        int o = bsumA[b] + block_excl_scan(v, t);
        if (i < m8) { offs8[i] = o; cur8[i] = o; }
    } else {
        int r = (b - blkA) * 256 + t;
        int v = (r < n) ? deg[r] : 0;
        int o = bsumB[b - blkA] + block_excl_scan(v, t);
        if (r < n) {
            offs[r] = o;
            if (r == n - 1) offs[n] = o + v;
        }
    }
}

// ---------- K5: sharded fill. rec8[pos] = {col|t0h<<16, t1h|t2h<<16} ----------
// shard = blockIdx&7 -> under round-robin dispatch, one XCD owns each shard region.
__global__ __launch_bounds__(256) void fill_kernel(const int* __restrict__ eidx,
        const float* __restrict__ TT, int* __restrict__ cur8,
        uint2* __restrict__ rec8, int E, int n) {
    int e = blockIdx.x * 256 + threadIdx.x;
    if (e >= E) return;
    int row = eidx[e];
    unsigned col = (unsigned)eidx[(size_t)E + e];
    unsigned h0 = __half_as_ushort(__float2half_rn(TT[e * 3 + 0]));
    unsigned h1 = __half_as_ushort(__float2half_rn(TT[e * 3 + 1]));
    unsigned h2 = __half_as_ushort(__float2half_rn(TT[e * 3 + 2]));
    int s = blockIdx.x & (NSH - 1);
    int pos = atomicAdd(&cur8[(size_t)s * n + row], 1);
    rec8[pos] = make_uint2(col | (h0 << 16), h1 | (h2 << 16));
}

// ---------- K6: repack 8 shard-CSRs into the single final CSR ----------
// lane = rloc*8 + s : 8 rows per wave, 32 rows per block; dest region per block
// is a contiguous ~4KB slice of rec -> written by exactly one block.
__global__ __launch_bounds__(256) void repack_kernel(const int* __restrict__ hist8,
        const int* __restrict__ offs8, const int* __restrict__ offs,
        const uint2* __restrict__ rec8, uint2* __restrict__ rec, int n) {
    int t = threadIdx.x;
    int lane = t & 63, wv = t >> 6;
    int s = lane & 7, rloc = lane >> 3;
    int r = blockIdx.x * 32 + wv * 8 + rloc;
    int len = 0, src = 0;
    if (r < n) {
        size_t idx = (size_t)s * n + r;
        len = hist8[idx];
        src = offs8[idx];
    }
    int exc = len;
#pragma unroll
    for (int o = 1; o < 8; o <<= 1) {
        int u = __shfl_up(exc, o);
        if ((lane & 7) >= o) exc += u;
    }
    exc -= len;
    if (r < n) {
        int dst = offs[r] + exc;
        for (int i = 0; i < len; ++i) rec[dst + i] = rec8[src + i];
    }
}

// ---------- K7: fused CSR aggregate (LDS z bf16) + MFMA gemm (unchanged) ----------
__device__ __forceinline__ void edge_fma(uint2 rc, const unsigned* __restrict__ xb2, int lane,
        float& a0l, float& a0h, float& a1l, float& a1h, float& a2l, float& a2h) {
    int c = rc.x & 0xffffu;
    float t0 = __half2float(__ushort_as_half((unsigned short)(rc.x >> 16)));
    float t1 = __half2float(__ushort_as_half((unsigned short)(rc.y & 0xffffu)));
    float t2 = __half2float(__ushort_as_half((unsigned short)(rc.y >> 16)));
    unsigned u = xb2[(size_t)c * 64 + lane];
    float xl = __uint_as_float(u << 16), xh = __uint_as_float(u & 0xffff0000u);
    a0l = fmaf(t0, xl, a0l); a0h = fmaf(t0, xh, a0h);
    a1l = fmaf(t1, xl, a1l); a1h = fmaf(t1, xh, a1h);
    a2l = fmaf(t2, xl, a2l); a2h = fmaf(t2, xh, a2h);
}

__global__ __launch_bounds__(256) void fused_kernel(const uint2* __restrict__ rec,
        const int* __restrict__ offs, const unsigned* __restrict__ xb2,
        const bf16x8* __restrict__ wbf, const float* __restrict__ bias,
        float* __restrict__ out, int n) {
    __shared__ short zs16[RPB][ZPAD];
    int lane = threadIdx.x & 63, wv = threadIdx.x >> 6;
    int n0 = blockIdx.x * RPB;

#pragma unroll
    for (int pass = 0; pass < RPB / 4; ++pass) {
        int j = pass * 4 + wv;
        int r = n0 + j;
        float a0l = 0, a0h = 0, a1l = 0, a1h = 0, a2l = 0, a2h = 0;
        if (r < n) {
            int p = offs[r], pe = offs[r + 1];
            for (; p + 4 <= pe; p += 4) {
                uint2 r0 = rec[p], r1 = rec[p + 1], r2 = rec[p + 2], r3 = rec[p + 3];
                edge_fma(r0, xb2, lane, a0l, a0h, a1l, a1h, a2l, a2h);
                edge_fma(r1, xb2, lane, a0l, a0h, a1l, a1h, a2l, a2h);
                edge_fma(r2, xb2, lane, a0l, a0h, a1l, a1h, a2l, a2h);
                edge_fma(r3, xb2, lane, a0l, a0h, a1l, a1h, a2l, a2h);
            }
            for (; p < pe; ++p)
                edge_fma(rec[p], xb2, lane, a0l, a0h, a1l, a1h, a2l, a2h);
        }
        *(unsigned*)&zs16[j][0 * DIM + 2 * lane] = pkbf(a0l, a0h);
        *(unsigned*)&zs16[j][1 * DIM + 2 * lane] = pkbf(a1l, a1h);
        *(unsigned*)&zs16[j][2 * DIM + 2 * lane] = pkbf(a2l, a2h);
    }
    __syncthreads();

    int quad = lane >> 4, m = lane & 15;
    int nt0 = wv * 2, nt1 = wv * 2 + 1;
    f32x4 acc0 = {0.f, 0.f, 0.f, 0.f}, acc1 = {0.f, 0.f, 0.f, 0.f};
#pragma unroll
    for (int kt = 0; kt < 12; ++kt) {
        bf16x8 a  = *(const bf16x8*)&zs16[m][kt * 32 + quad * 8];
        bf16x8 b0 = wbf[(kt * 8 + nt0) * 64 + lane];
        bf16x8 b1 = wbf[(kt * 8 + nt1) * 64 + lane];
        acc0 = __builtin_amdgcn_mfma_f32_16x16x32_bf16(a, b0, acc0, 0, 0, 0);
        acc1 = __builtin_amdgcn_mfma_f32_16x16x32_bf16(a, b1, acc1, 0, 0, 0);
    }
    float bi0 = bias[nt0 * 16 + m], bi1 = bias[nt1 * 16 + m];
#pragma unroll
    for (int rr = 0; rr < 4; ++rr) {
        int node = n0 + quad * 4 + rr;
        if (node < n) {
            out[(size_t)node * DIM + nt0 * 16 + m] = acc0[rr] + bi0;
            out[(size_t)node * DIM + nt1 * 16 + m] = acc1[rr] + bi1;
        }
    }
}

extern "C" void kernel_launch(void* const* d_in, const int* in_sizes, int n_in,
                              void* d_out, int out_size, void* d_ws, size_t ws_size,
                              hipStream_t stream) {
    const float* x    = (const float*)d_in[0];
    const float* TT   = (const float*)d_in[1];
    const float* w    = (const float*)d_in[2];
    const float* bias = (const float*)d_in[3];
    const int*   eidx = (const int*)d_in[4];
    float* out = (float*)d_out;

    int n = in_sizes[0] / DIM;   // 50000 (< 65536: col packs in 16 bits)
    int E = in_sizes[1] / KK;    // 800000
    int m8 = NSH * n;            // 400000 shard-histogram entries

    char* ws = (char*)d_ws;
    size_t o = 0;
    auto take = [&](size_t b) { void* p = ws + o; o += (b + 255) & ~(size_t)255; return p; };
    uint2*    rec   = (uint2*)take((size_t)E * 8);
    uint2*    rec8  = (uint2*)take((size_t)E * 8);
    int*      hist8 = (int*)take((size_t)m8 * 4);
    int*      offs8 = (int*)take((size_t)m8 * 4);
    int*      cur8  = (int*)take((size_t)m8 * 4);
    int*      deg   = (int*)take((size_t)n * 4);
    int*      offs  = (int*)take((size_t)(n + 1) * 4);
    int*      bsumA = (int*)take((size_t)2048 * 4);
    int*      bsumB = (int*)take((size_t)256 * 4);
    bf16x8*   wbf   = (bf16x8*)take((size_t)12 * 8 * 64 * 16);
    unsigned* xb2   = (unsigned*)take((size_t)n * DIM * 2);
    (void)ws_size;

    hipMemsetAsync(hist8, 0, (size_t)m8 * 4, stream);

    int xq = n * DIM / 4;                 // 1.6M float4s
    int xblk = (xq + 255) / 256;          // 6250
    int eblk = (E + 255) / 256;           // 3125
    int blkA = (m8 + 255) / 256;          // 1563
    int blkB = (n + 255) / 256;           // 196

    k1_kernel<<<xblk + 24 + eblk, 256, 0, stream>>>(
        x, w, eidx, (uint2*)xb2, wbf, hist8, xq, xblk, E, n);
    scan1_kernel<<<blkA + blkB, 256, 0, stream>>>(hist8, bsumA, deg, bsumB, m8, n, blkA);
    scan2_kernel<<<2, 256, 0, stream>>>(bsumA, blkA, bsumB, blkB);
    scan3_kernel<<<blkA + blkB, 256, 0, stream>>>(hist8, bsumA, deg, bsumB,
                                                  offs8, cur8, offs, m8, n, blkA);
    fill_kernel<<<eblk, 256, 0, stream>>>(eidx, TT, cur8, rec8, E, n);
    repack_kernel<<<(n + 31) / 32, 256, 0, stream>>>(hist8, offs8, offs, rec8, rec, n);
    fused_kernel<<<(n + RPB - 1) / RPB, 256, 0, stream>>>(rec, offs, xb2, wbf, bias, out, n);
}